// Round 6
// baseline (9492.945 us; speedup 1.0000x reference)
//
#include <hip/hip_runtime.h>
#include <hip/hip_bf16.h>

// ---------------- problem constants ----------------
constexpr int BATCH   = 32768;
constexpr int STATE_N = 64;
constexpr int HDIM    = 1024;
constexpr int KCODES  = 256;
constexpr int DDIM    = 128;
constexpr int GGRP    = 8;
constexpr int BG      = BATCH * GGRP;          // 262144 vectors
constexpr float BETA   = 0.25f;
constexpr float LN_EPS = 1e-5f;

constexpr long long DEC_OFF = 1;                                  // decoded at out+1
constexpr long long PPL_OFF = 1 + (long long)BATCH * STATE_N;     // 2097153
constexpr long long IDX_OFF = PPL_OFF + 1;                        // 2097154

typedef short bf16x8 __attribute__((ext_vector_type(8)));
typedef float f32x4  __attribute__((ext_vector_type(4)));

__device__ __forceinline__ ushort f2b(float f) {
    unsigned u = __float_as_uint(f);
    return (ushort)((u + 0x7fff + ((u >> 16) & 1)) >> 16);   // RNE, no NaN inputs here
}

__device__ __forceinline__ void gld_lds16(const void* g, const ushort* lds) {
    __builtin_amdgcn_global_load_lds(
        (const __attribute__((address_space(1))) unsigned*)g,
        (__attribute__((address_space(3))) unsigned*)lds, 16, 0, 0);
}

// ---------------- fp32 SGEMM, double-buffered, 1 barrier/K-step ----------------
// C = op(A[M,K] @ W[K,N] + bias).  M%128==0, N%128==0, K%16==0.
// Per-output-element FMA order is k=0..K-1 sequential -> bit-identical to the
// previous sgemm128 (idx near-tie margin preserved).
template <int RELU>
__global__ __launch_bounds__(256, 2)
void sgemm_db(const float* __restrict__ A, const float* __restrict__ W,
              const float* __restrict__ bias, float* __restrict__ C,
              int M, int N, int K)
{
    __shared__ float As[2][16][128];
    __shared__ float Bs[2][16][128];

    const int t  = threadIdx.x;
    const int bm = blockIdx.y * 128;
    const int bn = blockIdx.x * 128;
    const int tx = t & 15;
    const int ty = t >> 4;

    float4 acc[2][2][4];
#pragma unroll
    for (int a = 0; a < 2; ++a)
#pragma unroll
        for (int b = 0; b < 2; ++b)
#pragma unroll
            for (int i = 0; i < 4; ++i)
                acc[a][b][i] = make_float4(0.f, 0.f, 0.f, 0.f);

    // staging assignment: A row ar, k-offset ak (0/8); B k-row bk, col offset bn8
    const int ar  = t & 127;
    const int ak  = (t >> 7) * 8;
    const int bk  = t >> 4;          // 0..15
    const int bn8 = (t & 15) * 8;    // 0..120

    const float* Ap = A + (long long)(bm + ar) * K + ak;
    const float* Wp = W + (long long)bk * N + bn + bn8;

    float4 ra0, ra1, rb0, rb1;

    // prologue: slab 0 -> buf 0
    ra0 = *(const float4*)(Ap);
    ra1 = *(const float4*)(Ap + 4);
    rb0 = *(const float4*)(Wp);
    rb1 = *(const float4*)(Wp + 4);
    As[0][ak + 0][ar] = ra0.x; As[0][ak + 1][ar] = ra0.y;
    As[0][ak + 2][ar] = ra0.z; As[0][ak + 3][ar] = ra0.w;
    As[0][ak + 4][ar] = ra1.x; As[0][ak + 5][ar] = ra1.y;
    As[0][ak + 6][ar] = ra1.z; As[0][ak + 7][ar] = ra1.w;
    *(float4*)&Bs[0][bk][bn8]     = rb0;
    *(float4*)&Bs[0][bk][bn8 + 4] = rb1;

    const int S = K / 16;
    int cur = 0;

    for (int s = 0; s < S; ++s) {
        if (s + 1 < S) {
            const float* Ap2 = Ap + (s + 1) * 16;
            const float* Wp2 = Wp + (long long)(s + 1) * 16 * N;
            ra0 = *(const float4*)(Ap2);
            ra1 = *(const float4*)(Ap2 + 4);
            rb0 = *(const float4*)(Wp2);
            rb1 = *(const float4*)(Wp2 + 4);
        }
        __syncthreads();   // buf[cur] writes (prologue / prev tail) now visible

#pragma unroll
        for (int k = 0; k < 16; ++k) {
            float4 a0 = *(const float4*)&As[cur][k][ty * 4];
            float4 a1 = *(const float4*)&As[cur][k][64 + ty * 4];
            float4 b0 = *(const float4*)&Bs[cur][k][tx * 4];
            float4 b1 = *(const float4*)&Bs[cur][k][64 + tx * 4];
            const float* a0p = (const float*)&a0;
            const float* a1p = (const float*)&a1;
#pragma unroll
            for (int i = 0; i < 4; ++i) {
                float s0 = a0p[i];
                float s1 = a1p[i];
                acc[0][0][i].x += s0 * b0.x; acc[0][0][i].y += s0 * b0.y;
                acc[0][0][i].z += s0 * b0.z; acc[0][0][i].w += s0 * b0.w;
                acc[0][1][i].x += s0 * b1.x; acc[0][1][i].y += s0 * b1.y;
                acc[0][1][i].z += s0 * b1.z; acc[0][1][i].w += s0 * b1.w;
                acc[1][0][i].x += s1 * b0.x; acc[1][0][i].y += s1 * b0.y;
                acc[1][0][i].z += s1 * b0.z; acc[1][0][i].w += s1 * b0.w;
                acc[1][1][i].x += s1 * b1.x; acc[1][1][i].y += s1 * b1.y;
                acc[1][1][i].z += s1 * b1.z; acc[1][1][i].w += s1 * b1.w;
            }
        }

        if (s + 1 < S) {
            const int nb = cur ^ 1;     // safe: all waves passed top barrier of s,
                                        // so none still reads buf[nb] (last read s-1)
            As[nb][ak + 0][ar] = ra0.x; As[nb][ak + 1][ar] = ra0.y;
            As[nb][ak + 2][ar] = ra0.z; As[nb][ak + 3][ar] = ra0.w;
            As[nb][ak + 4][ar] = ra1.x; As[nb][ak + 5][ar] = ra1.y;
            As[nb][ak + 6][ar] = ra1.z; As[nb][ak + 7][ar] = ra1.w;
            *(float4*)&Bs[nb][bk][bn8]     = rb0;
            *(float4*)&Bs[nb][bk][bn8 + 4] = rb1;
            cur = nb;
        }
    }

    // epilogue: vector stores (N % 128 == 0 here)
#pragma unroll
    for (int rb = 0; rb < 2; ++rb) {
#pragma unroll
        for (int i = 0; i < 4; ++i) {
            const int row = bm + rb * 64 + ty * 4 + i;
#pragma unroll
            for (int cb = 0; cb < 2; ++cb) {
                const int col = bn + cb * 64 + tx * 4;
                float4 v = acc[rb][cb][i];
                const float4 bv = *(const float4*)&bias[col];
                v.x += bv.x; v.y += bv.y; v.z += bv.z; v.w += bv.w;
                if (RELU) {
                    v.x = fmaxf(v.x, 0.f); v.y = fmaxf(v.y, 0.f);
                    v.z = fmaxf(v.z, 0.f); v.w = fmaxf(v.w, 0.f);
                }
                *(float4*)&C[(long long)row * N + col] = v;
            }
        }
    }
}

// ---------------- generic fp32 SGEMM (kept for enc_w4: N=128 grid-x=1) ----------------
template <int RELU>
__global__ __launch_bounds__(256, 2)
void sgemm128(const float* __restrict__ A, const float* __restrict__ W,
              const float* __restrict__ bias, float* __restrict__ C,
              int M, int N, int K)
{
    __shared__ float As[8][128];
    __shared__ float Bs[8][128];

    const int t  = threadIdx.x;
    const int bm = blockIdx.y * 128;
    const int bn = blockIdx.x * 128;
    const int tx = t & 15;
    const int ty = t >> 4;

    float4 acc[2][2][4];
#pragma unroll
    for (int a = 0; a < 2; ++a)
#pragma unroll
        for (int b = 0; b < 2; ++b)
#pragma unroll
            for (int i = 0; i < 4; ++i)
                acc[a][b][i] = make_float4(0.f, 0.f, 0.f, 0.f);

    const int am  = t & 127;
    const int ak  = (t >> 7) * 4;
    const int bk  = t >> 5;
    const int bn4 = (t & 31) * 4;

    for (int k0 = 0; k0 < K; k0 += 8) {
        __syncthreads();
        float4 av = *(const float4*)&A[(long long)(bm + am) * K + k0 + ak];
        As[ak + 0][am] = av.x;
        As[ak + 1][am] = av.y;
        As[ak + 2][am] = av.z;
        As[ak + 3][am] = av.w;
        float4 bv = make_float4(0.f, 0.f, 0.f, 0.f);
        if (bn + bn4 < N)
            bv = *(const float4*)&W[(long long)(k0 + bk) * N + bn + bn4];
        *(float4*)&Bs[bk][bn4] = bv;
        __syncthreads();

#pragma unroll
        for (int k = 0; k < 8; ++k) {
            float4 a0 = *(const float4*)&As[k][ty * 4];
            float4 a1 = *(const float4*)&As[k][64 + ty * 4];
            float4 b0 = *(const float4*)&Bs[k][tx * 4];
            float4 b1 = *(const float4*)&Bs[k][64 + tx * 4];
            const float* a0p = (const float*)&a0;
            const float* a1p = (const float*)&a1;
#pragma unroll
            for (int i = 0; i < 4; ++i) {
                float s0 = a0p[i];
                float s1 = a1p[i];
                acc[0][0][i].x += s0 * b0.x; acc[0][0][i].y += s0 * b0.y;
                acc[0][0][i].z += s0 * b0.z; acc[0][0][i].w += s0 * b0.w;
                acc[0][1][i].x += s0 * b1.x; acc[0][1][i].y += s0 * b1.y;
                acc[0][1][i].z += s0 * b1.z; acc[0][1][i].w += s0 * b1.w;
                acc[1][0][i].x += s1 * b0.x; acc[1][0][i].y += s1 * b0.y;
                acc[1][0][i].z += s1 * b0.z; acc[1][0][i].w += s1 * b0.w;
                acc[1][1][i].x += s1 * b1.x; acc[1][1][i].y += s1 * b1.y;
                acc[1][1][i].z += s1 * b1.z; acc[1][1][i].w += s1 * b1.w;
            }
        }
    }

#pragma unroll
    for (int rb = 0; rb < 2; ++rb) {
#pragma unroll
        for (int i = 0; i < 4; ++i) {
            int row = bm + rb * 64 + ty * 4 + i;
#pragma unroll
            for (int cb = 0; cb < 2; ++cb) {
                const float* vp = (const float*)&acc[rb][cb][i];
#pragma unroll
                for (int j = 0; j < 4; ++j) {
                    int col = bn + cb * 64 + tx * 4 + j;
                    if (col < N) {
                        float r = vp[j] + bias[col];
                        if (RELU) r = fmaxf(r, 0.f);
                        C[(long long)row * N + col] = r;
                    }
                }
            }
        }
    }
}

// ---------------- bf16 MFMA GEMM: C = op(A[M,K] @ Bt[N,K]^T + bias) ----------------
template <int RELU, int OUT_BF16>
__global__ __launch_bounds__(256, 2)
void hgemm128(const ushort* __restrict__ A, const ushort* __restrict__ Bt,
              const float* __restrict__ bias, void* __restrict__ Cout,
              int M, int N, int K)
{
    __shared__ ushort As[128 * 32];
    __shared__ ushort Bs[128 * 32];

    const int t    = threadIdx.x;
    const int lane = t & 63;
    const int w    = t >> 6;
    const int wr   = w >> 1;
    const int wc   = w & 1;
    const int bm   = blockIdx.y * 128;
    const int bn   = blockIdx.x * 128;

    f32x4 acc[4][4] = {};

    const int sr = lane >> 2;
    const int sk = (lane & 3) * 8;

    const ushort* Abase = A  + (long long)bm * K;
    const ushort* Bbase = Bt + (long long)bn * K;

    for (int k0 = 0; k0 < K; k0 += 32) {
        __syncthreads();
#pragma unroll
        for (int i = 0; i < 2; ++i) {
            const int r = w * 32 + i * 16 + sr;
            gld_lds16(Abase + (long long)r * K + k0 + sk, &As[(w * 32 + i * 16) * 32]);
            gld_lds16(Bbase + (long long)r * K + k0 + sk, &Bs[(w * 32 + i * 16) * 32]);
        }
        __syncthreads();

        bf16x8 af[4], bfr[4];
#pragma unroll
        for (int mi = 0; mi < 4; ++mi)
            af[mi] = *(const bf16x8*)&As[(wr * 64 + mi * 16 + (lane & 15)) * 32 + (lane >> 4) * 8];
#pragma unroll
        for (int ni = 0; ni < 4; ++ni)
            bfr[ni] = *(const bf16x8*)&Bs[(wc * 64 + ni * 16 + (lane & 15)) * 32 + (lane >> 4) * 8];
#pragma unroll
        for (int mi = 0; mi < 4; ++mi)
#pragma unroll
            for (int ni = 0; ni < 4; ++ni)
                acc[mi][ni] = __builtin_amdgcn_mfma_f32_16x16x32_bf16(af[mi], bfr[ni], acc[mi][ni], 0, 0, 0);
    }

    const int cl = lane & 15;
    const int rg = lane >> 4;
    float bv[4];
#pragma unroll
    for (int ni = 0; ni < 4; ++ni) {
        int col = bn + wc * 64 + ni * 16 + cl;
        bv[ni] = (col < N) ? bias[col] : 0.f;
    }
#pragma unroll
    for (int mi = 0; mi < 4; ++mi) {
#pragma unroll
        for (int ni = 0; ni < 4; ++ni) {
            int col = bn + wc * 64 + ni * 16 + cl;
            if (col < N) {
#pragma unroll
                for (int j = 0; j < 4; ++j) {
                    int row = bm + wr * 64 + mi * 16 + rg * 4 + j;
                    float v = acc[mi][ni][j] + bv[ni];
                    if (RELU) v = fmaxf(v, 0.f);
                    if (OUT_BF16) ((ushort*)Cout)[(long long)row * N + col] = f2b(v);
                    else          ((float*)Cout)[(long long)row * N + col] = v;
                }
            }
        }
    }
}

// ---------------- W[K,N] f32 -> Bt[Npad,K] bf16 ----------------
__global__ __launch_bounds__(256)
void transpose_to_bf16(const float* __restrict__ W, ushort* __restrict__ Bt,
                       int K, int N, int Npad)
{
    __shared__ float tile[32][33];
    const int t  = threadIdx.x;
    const int n0 = blockIdx.x * 32;
    const int k0 = blockIdx.y * 32;
    const int tc = t & 31;
    const int tr = t >> 5;
#pragma unroll
    for (int i = 0; i < 4; ++i) {
        int kk = tr + i * 8;
        float v = 0.f;
        if (n0 + tc < N) v = W[(long long)(k0 + kk) * N + n0 + tc];
        tile[kk][tc] = v;
    }
    __syncthreads();
#pragma unroll
    for (int i = 0; i < 4; ++i) {
        int nn = tr + i * 8;
        Bt[(long long)(n0 + nn) * K + k0 + tc] = f2b(tile[tc][nn]);
    }
}

// ---------------- LayerNorm + ReLU, in place ----------------
__global__ __launch_bounds__(256)
void ln_relu_kernel(float* __restrict__ h, const float* __restrict__ g,
                    const float* __restrict__ b, int M)
{
    const int wave = threadIdx.x >> 6;
    const int lane = threadIdx.x & 63;
    const int row  = blockIdx.x * 4 + wave;
    if (row >= M) return;
    float* rp = h + (long long)row * HDIM;

    float4 v[4];
    float s = 0.f, ss = 0.f;
#pragma unroll
    for (int c = 0; c < 4; ++c) {
        v[c] = *(const float4*)&rp[c * 256 + lane * 4];
        s  += v[c].x + v[c].y + v[c].z + v[c].w;
        ss += v[c].x * v[c].x + v[c].y * v[c].y + v[c].z * v[c].z + v[c].w * v[c].w;
    }
#pragma unroll
    for (int o = 32; o > 0; o >>= 1) {
        s  += __shfl_xor(s, o);
        ss += __shfl_xor(ss, o);
    }
    const float mu  = s * (1.f / HDIM);
    const float var = ss * (1.f / HDIM) - mu * mu;
    const float inv = rsqrtf(var + LN_EPS);
#pragma unroll
    for (int c = 0; c < 4; ++c) {
        int col = c * 256 + lane * 4;
        float4 gg = *(const float4*)&g[col];
        float4 bb = *(const float4*)&b[col];
        float4 o4;
        o4.x = fmaxf((v[c].x - mu) * inv * gg.x + bb.x, 0.f);
        o4.y = fmaxf((v[c].y - mu) * inv * gg.y + bb.y, 0.f);
        o4.z = fmaxf((v[c].z - mu) * inv * gg.z + bb.z, 0.f);
        o4.w = fmaxf((v[c].w - mu) * inv * gg.w + bb.w, 0.f);
        *(float4*)&rp[col] = o4;
    }
}

// ---------------- codebook squared norms ----------------
__global__ void c2_kernel(const float* __restrict__ cb, float* __restrict__ c2)
{
    const int k = threadIdx.x;
    const float4* cp = (const float4*)(cb + (long long)k * DDIM);
    float s = 0.f;
#pragma unroll
    for (int i = 0; i < 32; ++i) {
        float4 c = cp[i];
        s += c.x * c.x + c.y * c.y + c.z * c.z + c.w * c.w;
    }
    c2[k] = s;
}

// ---------------- zero accumulators ----------------
__global__ void zero_kernel(int* __restrict__ hist, float* __restrict__ loss)
{
    int t = threadIdx.x;
    if (t < 256) hist[t] = 0;
    if (t == 256) *loss = 0.f;
}

// ---------------- VQ as register-tiled GEMM (round-5 proven) ----------------
__global__ __launch_bounds__(256, 2)
void vq_gemm_kernel(const float* __restrict__ z, const float* __restrict__ cb,
                    const float* __restrict__ c2, ushort* __restrict__ zq,
                    float* __restrict__ idx_out, float* __restrict__ loss_sum,
                    int* __restrict__ hist)
{
    __shared__ __align__(16) char smem[49152];
    float (*Zs)[128] = (float (*)[128])smem;                 // [32 k][128 z]  16 KB
    float (*Cs)[256] = (float (*)[256])(smem + 16384);       // [32 k][256 c]  32 KB
    unsigned long long* red = (unsigned long long*)smem;     // [128][16] aliases Zs
    int* lhist    = (int*)(smem + 16384);                    // aliases Cs
    int* bestk_sh = (int*)(smem + 16384 + 1024);             // aliases Cs+1KB

    const int t  = threadIdx.x;
    const int tx = t & 15;
    const int ty = t >> 4;
    const int v0 = blockIdx.x * 128;

    float acc[8][16];
    float z2p[8];
#pragma unroll
    for (int i = 0; i < 8; ++i) {
        z2p[i] = 0.f;
#pragma unroll
        for (int j = 0; j < 16; ++j) acc[i][j] = 0.f;
    }

    const int svl = t >> 1;
    const int skf = (t & 1) * 16;

    for (int k0 = 0; k0 < DDIM; k0 += 32) {
        __syncthreads();
        {
            const float4* src = (const float4*)&z[(long long)(v0 + svl) * DDIM + k0 + skf];
#pragma unroll
            for (int q = 0; q < 4; ++q) {
                float4 f = src[q];
                Zs[skf + q * 4 + 0][svl] = f.x;
                Zs[skf + q * 4 + 1][svl] = f.y;
                Zs[skf + q * 4 + 2][svl] = f.z;
                Zs[skf + q * 4 + 3][svl] = f.w;
            }
        }
        {
            const float4* src = (const float4*)&cb[(long long)t * DDIM + k0];
#pragma unroll
            for (int q = 0; q < 8; ++q) {
                float4 f = src[q];
                Cs[q * 4 + 0][t] = f.x;
                Cs[q * 4 + 1][t] = f.y;
                Cs[q * 4 + 2][t] = f.z;
                Cs[q * 4 + 3][t] = f.w;
            }
        }
        __syncthreads();

#pragma unroll 8
        for (int k = 0; k < 32; ++k) {
            float4 a0 = *(const float4*)&Zs[k][ty * 8];
            float4 a1 = *(const float4*)&Zs[k][ty * 8 + 4];
            float a[8] = {a0.x, a0.y, a0.z, a0.w, a1.x, a1.y, a1.z, a1.w};
            float b[16];
#pragma unroll
            for (int j = 0; j < 16; ++j) b[j] = Cs[k][tx + 16 * j];
#pragma unroll
            for (int i = 0; i < 8; ++i) z2p[i] += a[i] * a[i];
#pragma unroll
            for (int j = 0; j < 16; ++j)
#pragma unroll
                for (int i = 0; i < 8; ++i)
                    acc[i][j] += a[i] * b[j];
        }
    }

    __syncthreads();
    float c2v[16];
#pragma unroll
    for (int j = 0; j < 16; ++j) c2v[j] = c2[tx + 16 * j];
    lhist[t] = 0;
#pragma unroll
    for (int i = 0; i < 8; ++i) {
        float bd = 3.4e38f;
        int bj = 0;
#pragma unroll
        for (int j = 0; j < 16; ++j) {
            float d = (z2p[i] - 2.f * acc[i][j]) + c2v[j];
            if (d < bd) { bd = d; bj = j; }
        }
        red[(ty * 8 + i) * 16 + tx] =
            ((unsigned long long)__float_as_uint(bd) << 32) | (unsigned)(tx + 16 * bj);
    }
    __syncthreads();

    if (t < 128) {
        unsigned long long m = red[t * 16];
#pragma unroll
        for (int j = 1; j < 16; ++j) {
            unsigned long long c = red[t * 16 + j];
            if (c < m) m = c;
        }
        int bk = (int)(m & 0xffffffffu);
        bestk_sh[t] = bk;
        idx_out[v0 + t] = (float)bk;
        atomicAdd(&lhist[bk], 1);
    }
    __syncthreads();

    {
        const int zl = t >> 1, half = t & 1;
        const int bk = bestk_sh[zl];
        const float4* zp = (const float4*)&z[(long long)(v0 + zl) * DDIM + half * 64];
        const float4* cp = (const float4*)&cb[(long long)bk * DDIM + half * 64];
        uint4* zqp = (uint4*)&zq[(long long)(v0 + zl) * DDIM + half * 64];
        float lsum = 0.f;
#pragma unroll
        for (int q = 0; q < 8; ++q) {
            float4 z0 = zp[q * 2], z1 = zp[q * 2 + 1];
            float4 c0 = cp[q * 2], c1 = cp[q * 2 + 1];
            float dx, dy, dz, dw;
            dx = c0.x - z0.x; dy = c0.y - z0.y; dz = c0.z - z0.z; dw = c0.w - z0.w;
            lsum += dx * dx + dy * dy + dz * dz + dw * dw;
            dx = c1.x - z1.x; dy = c1.y - z1.y; dz = c1.z - z1.z; dw = c1.w - z1.w;
            lsum += dx * dx + dy * dy + dz * dz + dw * dw;
            uint4 pk;
            pk.x = (unsigned)f2b(c0.x) | ((unsigned)f2b(c0.y) << 16);
            pk.y = (unsigned)f2b(c0.z) | ((unsigned)f2b(c0.w) << 16);
            pk.z = (unsigned)f2b(c1.x) | ((unsigned)f2b(c1.y) << 16);
            pk.w = (unsigned)f2b(c1.z) | ((unsigned)f2b(c1.w) << 16);
            zqp[q] = pk;
        }
#pragma unroll
        for (int o = 32; o > 0; o >>= 1) lsum += __shfl_xor(lsum, o);
        if ((t & 63) == 0) atomicAdd(loss_sum, lsum);
    }
    __syncthreads();
    int h = lhist[t];
    if (h) atomicAdd(&hist[t], h);
}

// ---------------- finalize ----------------
__global__ __launch_bounds__(256)
void finalize_kernel(const int* __restrict__ hist, const float* __restrict__ loss,
                     float* __restrict__ out)
{
    __shared__ float red[256];
    const int t = threadIdx.x;
    float e = (float)hist[t] / (float)BG;
    red[t] = -e * logf(e + 1e-10f);
    __syncthreads();
    for (int s = 128; s > 0; s >>= 1) {
        if (t < s) red[t] += red[t + s];
        __syncthreads();
    }
    if (t == 0) {
        out[0]       = (1.f + BETA) * (*loss) / (float)((long long)BG * DDIM);
        out[PPL_OFF] = expf(red[0]);
    }
}

// ---------------- launch ----------------
extern "C" void kernel_launch(void* const* d_in, const int* in_sizes, int n_in,
                              void* d_out, int out_size, void* d_ws, size_t ws_size,
                              hipStream_t stream)
{
    const float* x        = (const float*)d_in[0];
    const float* enc_w1   = (const float*)d_in[1];
    const float* enc_b1   = (const float*)d_in[2];
    const float* enc_w2   = (const float*)d_in[3];
    const float* enc_b2   = (const float*)d_in[4];
    const float* ln_g     = (const float*)d_in[5];
    const float* ln_b     = (const float*)d_in[6];
    const float* enc_w3   = (const float*)d_in[7];
    const float* enc_b3   = (const float*)d_in[8];
    const float* enc_w4   = (const float*)d_in[9];
    const float* enc_b4   = (const float*)d_in[10];
    const float* codebook = (const float*)d_in[11];
    const float* dec_w1   = (const float*)d_in[12];
    const float* dec_b1   = (const float*)d_in[13];
    const float* dec_w2   = (const float*)d_in[14];
    const float* dec_b2   = (const float*)d_in[15];
    const float* dec_w3   = (const float*)d_in[16];
    const float* dec_b3   = (const float*)d_in[17];
    float* out = (float*)d_out;

    constexpr size_t RESERVE = 8ull << 20;
    char* ws = (char*)d_ws;
    ushort* wt1 = (ushort*)ws;                          // [1024][1024] bf16, 2MB
    ushort* wt2 = (ushort*)(ws + (2ull << 20));         // [1024][1024] bf16, 2MB
    ushort* wt3 = (ushort*)(ws + (4ull << 20));         // [128][1024] bf16 zero-padded
    float*  c2  = (float*)(ws + (4ull << 20) + 262144);
    int*   hist = (int*)  (ws + (4ull << 20) + 262144 + 1024);
    float* loss = (float*)(ws + (4ull << 20) + 262144 + 2048);

    static const int cands[9] = {32768, 16384, 8192, 4096, 2048, 1024, 512, 256, 128};
    int chunk = 128;
    for (int i = 0; i < 9; ++i) {
        size_t need = RESERVE + 2ull * (size_t)cands[i] * HDIM * sizeof(float);
        if (need <= ws_size) { chunk = cands[i]; break; }
    }
    float* bufA = (float*)(ws + RESERVE);
    float* bufB = (float*)(ws + RESERVE + (size_t)chunk * HDIM * sizeof(float));

    const dim3 blk(256);

    zero_kernel<<<1, 512, 0, stream>>>(hist, loss);
    c2_kernel<<<1, 256, 0, stream>>>(codebook, c2);
    transpose_to_bf16<<<dim3(32, 32), blk, 0, stream>>>(dec_w1, wt1, HDIM, HDIM, HDIM);
    transpose_to_bf16<<<dim3(32, 32), blk, 0, stream>>>(dec_w2, wt2, HDIM, HDIM, HDIM);
    transpose_to_bf16<<<dim3(4, 32),  blk, 0, stream>>>(dec_w3, wt3, HDIM, STATE_N, 128);

    for (int c0 = 0; c0 < BATCH; c0 += chunk) {
        const float* xc = x + (long long)c0 * STATE_N;
        float* decC     = out + DEC_OFF + (long long)c0 * STATE_N;
        float* idxC     = out + IDX_OFF + (long long)c0 * GGRP;

        // ---- encoder (fp32, double-buffered; bit-identical k-order) ----
        sgemm_db<1><<<dim3(8, chunk / 128), blk, 0, stream>>>(xc,   enc_w1, enc_b1, bufA, chunk, HDIM, STATE_N);
        sgemm_db<0><<<dim3(8, chunk / 128), blk, 0, stream>>>(bufA, enc_w2, enc_b2, bufB, chunk, HDIM, HDIM);
        ln_relu_kernel<<<chunk / 4, 256, 0, stream>>>(bufB, ln_g, ln_b, chunk);
        sgemm_db<1><<<dim3(8, chunk / 128), blk, 0, stream>>>(bufB, enc_w3, enc_b3, bufA, chunk, HDIM, HDIM);
        sgemm128<0><<<dim3(1, chunk * GGRP / 128), blk, 0, stream>>>(bufA, enc_w4, enc_b4, bufB, chunk * GGRP, DDIM, DDIM);

        // ---- VQ (GEMM-structured fp32; writes bf16 z_q into bufA region) ----
        ushort* zqb = (ushort*)bufA;
        vq_gemm_kernel<<<chunk * GGRP / 128, blk, 0, stream>>>(bufB, codebook, c2, zqb, idxC, loss, hist);

        // ---- decoder (bf16 MFMA) ----
        ushort* g1b = (ushort*)bufB;
        ushort* g2b = (ushort*)(((char*)bufA) + (size_t)chunk * HDIM * sizeof(ushort));
        hgemm128<1, 1><<<dim3(8, chunk / 128), blk, 0, stream>>>(zqb, wt1, dec_b1, g1b, chunk, HDIM, HDIM);
        hgemm128<1, 1><<<dim3(8, chunk / 128), blk, 0, stream>>>(g1b, wt2, dec_b2, g2b, chunk, HDIM, HDIM);
        hgemm128<0, 0><<<dim3(1, chunk / 128), blk, 0, stream>>>(g2b, wt3, dec_b3, decC, chunk, STATE_N, HDIM);
    }

    finalize_kernel<<<1, 256, 0, stream>>>(hist, loss, out);
}

// Round 7
// 2473.604 us; speedup vs baseline: 3.8377x; 3.8377x over previous
//
#include <hip/hip_runtime.h>
#include <hip/hip_bf16.h>

// ---------------- problem constants ----------------
constexpr int BATCH   = 32768;
constexpr int STATE_N = 64;
constexpr int HDIM    = 1024;
constexpr int KCODES  = 256;
constexpr int DDIM    = 128;
constexpr int GGRP    = 8;
constexpr int BG      = BATCH * GGRP;          // 262144 vectors
constexpr float BETA   = 0.25f;
constexpr float LN_EPS = 1e-5f;

constexpr long long DEC_OFF = 1;                                  // decoded at out+1
constexpr long long PPL_OFF = 1 + (long long)BATCH * STATE_N;     // 2097153
constexpr long long IDX_OFF = PPL_OFF + 1;                        // 2097154

typedef short bf16x8 __attribute__((ext_vector_type(8)));
typedef float f32x4  __attribute__((ext_vector_type(4)));

__device__ __forceinline__ ushort f2b(float f) {
    unsigned u = __float_as_uint(f);
    return (ushort)((u + 0x7fff + ((u >> 16) & 1)) >> 16);   // RNE, no NaN inputs here
}

__device__ __forceinline__ void gld_lds16(const void* g, const ushort* lds) {
    __builtin_amdgcn_global_load_lds(
        (const __attribute__((address_space(1))) unsigned*)g,
        (__attribute__((address_space(3))) unsigned*)lds, 16, 0, 0);
}

// ---------------- fp32 SGEMM, single-buffer, K-step 32 ----------------
// C = op(A[M,K] @ W[K,N] + bias).  M%128==0, K%32==0, N%4==0 (our N: 1024/128).
// Inner FMA order per output element: k = 0..K-1 sequential -> bit-identical to
// round-5 sgemm128.  Staging registers are TRANSIENT (consumed into LDS before
// the compute loop) -- round-6 lesson: liveness across compute = scratch spill.
template <int RELU>
__global__ __launch_bounds__(256, 2)
void sgemm32(const float* __restrict__ A, const float* __restrict__ W,
             const float* __restrict__ bias, float* __restrict__ C,
             int M, int N, int K)
{
    __shared__ float As[32][128];
    __shared__ float Bs[32][128];

    const int t  = threadIdx.x;
    const int bm = blockIdx.y * 128;
    const int bn = blockIdx.x * 128;
    const int tx = t & 15;
    const int ty = t >> 4;

    float4 acc[2][2][4];
#pragma unroll
    for (int a = 0; a < 2; ++a)
#pragma unroll
        for (int b = 0; b < 2; ++b)
#pragma unroll
            for (int i = 0; i < 4; ++i)
                acc[a][b][i] = make_float4(0.f, 0.f, 0.f, 0.f);

    // staging: A row ar, 16 consecutive k (64B contiguous); B row bk, 16 cols
    const int ar   = t & 127;
    const int ak   = (t >> 7) * 16;       // 0 or 16
    const int bk   = t >> 3;              // 0..31
    const int bn16 = (t & 7) * 16;        // 0..112

    for (int k0 = 0; k0 < K; k0 += 32) {
        __syncthreads();
        {
            const float* ap = &A[(long long)(bm + ar) * K + k0 + ak];
            float4 a4[4];
#pragma unroll
            for (int q = 0; q < 4; ++q) a4[q] = *(const float4*)(ap + q * 4);
#pragma unroll
            for (int q = 0; q < 4; ++q) {
                As[ak + q * 4 + 0][ar] = a4[q].x;
                As[ak + q * 4 + 1][ar] = a4[q].y;
                As[ak + q * 4 + 2][ar] = a4[q].z;
                As[ak + q * 4 + 3][ar] = a4[q].w;
            }
            const float* wp = &W[(long long)(k0 + bk) * N + bn + bn16];
#pragma unroll
            for (int q = 0; q < 4; ++q)
                *(float4*)&Bs[bk][bn16 + q * 4] = *(const float4*)(wp + q * 4);
        }
        __syncthreads();

#pragma unroll 8
        for (int k = 0; k < 32; ++k) {
            float4 a0 = *(const float4*)&As[k][ty * 4];
            float4 a1 = *(const float4*)&As[k][64 + ty * 4];
            float4 b0 = *(const float4*)&Bs[k][tx * 4];
            float4 b1 = *(const float4*)&Bs[k][64 + tx * 4];
            const float* a0p = (const float*)&a0;
            const float* a1p = (const float*)&a1;
#pragma unroll
            for (int i = 0; i < 4; ++i) {
                float s0 = a0p[i];
                float s1 = a1p[i];
                acc[0][0][i].x += s0 * b0.x; acc[0][0][i].y += s0 * b0.y;
                acc[0][0][i].z += s0 * b0.z; acc[0][0][i].w += s0 * b0.w;
                acc[0][1][i].x += s0 * b1.x; acc[0][1][i].y += s0 * b1.y;
                acc[0][1][i].z += s0 * b1.z; acc[0][1][i].w += s0 * b1.w;
                acc[1][0][i].x += s1 * b0.x; acc[1][0][i].y += s1 * b0.y;
                acc[1][0][i].z += s1 * b0.z; acc[1][0][i].w += s1 * b0.w;
                acc[1][1][i].x += s1 * b1.x; acc[1][1][i].y += s1 * b1.y;
                acc[1][1][i].z += s1 * b1.z; acc[1][1][i].w += s1 * b1.w;
            }
        }
    }

    // epilogue: identical to round-5 (scalar guarded stores)
#pragma unroll
    for (int rb = 0; rb < 2; ++rb) {
#pragma unroll
        for (int i = 0; i < 4; ++i) {
            int row = bm + rb * 64 + ty * 4 + i;
#pragma unroll
            for (int cb = 0; cb < 2; ++cb) {
                const float* vp = (const float*)&acc[rb][cb][i];
#pragma unroll
                for (int j = 0; j < 4; ++j) {
                    int col = bn + cb * 64 + tx * 4 + j;
                    if (col < N) {
                        float r = vp[j] + bias[col];
                        if (RELU) r = fmaxf(r, 0.f);
                        C[(long long)row * N + col] = r;
                    }
                }
            }
        }
    }
}

// ---------------- bf16 MFMA GEMM: C = op(A[M,K] @ Bt[N,K]^T + bias) ----------------
template <int RELU, int OUT_BF16>
__global__ __launch_bounds__(256, 2)
void hgemm128(const ushort* __restrict__ A, const ushort* __restrict__ Bt,
              const float* __restrict__ bias, void* __restrict__ Cout,
              int M, int N, int K)
{
    __shared__ ushort As[128 * 32];
    __shared__ ushort Bs[128 * 32];

    const int t    = threadIdx.x;
    const int lane = t & 63;
    const int w    = t >> 6;
    const int wr   = w >> 1;
    const int wc   = w & 1;
    const int bm   = blockIdx.y * 128;
    const int bn   = blockIdx.x * 128;

    f32x4 acc[4][4] = {};

    const int sr = lane >> 2;
    const int sk = (lane & 3) * 8;

    const ushort* Abase = A  + (long long)bm * K;
    const ushort* Bbase = Bt + (long long)bn * K;

    for (int k0 = 0; k0 < K; k0 += 32) {
        __syncthreads();
#pragma unroll
        for (int i = 0; i < 2; ++i) {
            const int r = w * 32 + i * 16 + sr;
            gld_lds16(Abase + (long long)r * K + k0 + sk, &As[(w * 32 + i * 16) * 32]);
            gld_lds16(Bbase + (long long)r * K + k0 + sk, &Bs[(w * 32 + i * 16) * 32]);
        }
        __syncthreads();

        bf16x8 af[4], bfr[4];
#pragma unroll
        for (int mi = 0; mi < 4; ++mi)
            af[mi] = *(const bf16x8*)&As[(wr * 64 + mi * 16 + (lane & 15)) * 32 + (lane >> 4) * 8];
#pragma unroll
        for (int ni = 0; ni < 4; ++ni)
            bfr[ni] = *(const bf16x8*)&Bs[(wc * 64 + ni * 16 + (lane & 15)) * 32 + (lane >> 4) * 8];
#pragma unroll
        for (int mi = 0; mi < 4; ++mi)
#pragma unroll
            for (int ni = 0; ni < 4; ++ni)
                acc[mi][ni] = __builtin_amdgcn_mfma_f32_16x16x32_bf16(af[mi], bfr[ni], acc[mi][ni], 0, 0, 0);
    }

    const int cl = lane & 15;
    const int rg = lane >> 4;
    float bv[4];
#pragma unroll
    for (int ni = 0; ni < 4; ++ni) {
        int col = bn + wc * 64 + ni * 16 + cl;
        bv[ni] = (col < N) ? bias[col] : 0.f;
    }
#pragma unroll
    for (int mi = 0; mi < 4; ++mi) {
#pragma unroll
        for (int ni = 0; ni < 4; ++ni) {
            int col = bn + wc * 64 + ni * 16 + cl;
            if (col < N) {
#pragma unroll
                for (int j = 0; j < 4; ++j) {
                    int row = bm + wr * 64 + mi * 16 + rg * 4 + j;
                    float v = acc[mi][ni][j] + bv[ni];
                    if (RELU) v = fmaxf(v, 0.f);
                    if (OUT_BF16) ((ushort*)Cout)[(long long)row * N + col] = f2b(v);
                    else          ((float*)Cout)[(long long)row * N + col] = v;
                }
            }
        }
    }
}

// ---------------- W[K,N] f32 -> Bt[Npad,K] bf16 ----------------
__global__ __launch_bounds__(256)
void transpose_to_bf16(const float* __restrict__ W, ushort* __restrict__ Bt,
                       int K, int N, int Npad)
{
    __shared__ float tile[32][33];
    const int t  = threadIdx.x;
    const int n0 = blockIdx.x * 32;
    const int k0 = blockIdx.y * 32;
    const int tc = t & 31;
    const int tr = t >> 5;
#pragma unroll
    for (int i = 0; i < 4; ++i) {
        int kk = tr + i * 8;
        float v = 0.f;
        if (n0 + tc < N) v = W[(long long)(k0 + kk) * N + n0 + tc];
        tile[kk][tc] = v;
    }
    __syncthreads();
#pragma unroll
    for (int i = 0; i < 4; ++i) {
        int nn = tr + i * 8;
        Bt[(long long)(n0 + nn) * K + k0 + tc] = f2b(tile[tc][nn]);
    }
}

// ---------------- LayerNorm + ReLU, in place ----------------
__global__ __launch_bounds__(256)
void ln_relu_kernel(float* __restrict__ h, const float* __restrict__ g,
                    const float* __restrict__ b, int M)
{
    const int wave = threadIdx.x >> 6;
    const int lane = threadIdx.x & 63;
    const int row  = blockIdx.x * 4 + wave;
    if (row >= M) return;
    float* rp = h + (long long)row * HDIM;

    float4 v[4];
    float s = 0.f, ss = 0.f;
#pragma unroll
    for (int c = 0; c < 4; ++c) {
        v[c] = *(const float4*)&rp[c * 256 + lane * 4];
        s  += v[c].x + v[c].y + v[c].z + v[c].w;
        ss += v[c].x * v[c].x + v[c].y * v[c].y + v[c].z * v[c].z + v[c].w * v[c].w;
    }
#pragma unroll
    for (int o = 32; o > 0; o >>= 1) {
        s  += __shfl_xor(s, o);
        ss += __shfl_xor(ss, o);
    }
    const float mu  = s * (1.f / HDIM);
    const float var = ss * (1.f / HDIM) - mu * mu;
    const float inv = rsqrtf(var + LN_EPS);
#pragma unroll
    for (int c = 0; c < 4; ++c) {
        int col = c * 256 + lane * 4;
        float4 gg = *(const float4*)&g[col];
        float4 bb = *(const float4*)&b[col];
        float4 o4;
        o4.x = fmaxf((v[c].x - mu) * inv * gg.x + bb.x, 0.f);
        o4.y = fmaxf((v[c].y - mu) * inv * gg.y + bb.y, 0.f);
        o4.z = fmaxf((v[c].z - mu) * inv * gg.z + bb.z, 0.f);
        o4.w = fmaxf((v[c].w - mu) * inv * gg.w + bb.w, 0.f);
        *(float4*)&rp[col] = o4;
    }
}

// ---------------- codebook squared norms ----------------
__global__ void c2_kernel(const float* __restrict__ cb, float* __restrict__ c2)
{
    const int k = threadIdx.x;
    const float4* cp = (const float4*)(cb + (long long)k * DDIM);
    float s = 0.f;
#pragma unroll
    for (int i = 0; i < 32; ++i) {
        float4 c = cp[i];
        s += c.x * c.x + c.y * c.y + c.z * c.z + c.w * c.w;
    }
    c2[k] = s;
}

// ---------------- zero accumulators ----------------
__global__ void zero_kernel(int* __restrict__ hist, float* __restrict__ loss)
{
    int t = threadIdx.x;
    if (t < 256) hist[t] = 0;
    if (t == 256) *loss = 0.f;
}

// ---------------- VQ as register-tiled GEMM (round-5 proven) ----------------
__global__ __launch_bounds__(256, 2)
void vq_gemm_kernel(const float* __restrict__ z, const float* __restrict__ cb,
                    const float* __restrict__ c2, ushort* __restrict__ zq,
                    float* __restrict__ idx_out, float* __restrict__ loss_sum,
                    int* __restrict__ hist)
{
    __shared__ __align__(16) char smem[49152];
    float (*Zs)[128] = (float (*)[128])smem;                 // [32 k][128 z]  16 KB
    float (*Cs)[256] = (float (*)[256])(smem + 16384);       // [32 k][256 c]  32 KB
    unsigned long long* red = (unsigned long long*)smem;     // [128][16] aliases Zs
    int* lhist    = (int*)(smem + 16384);                    // aliases Cs
    int* bestk_sh = (int*)(smem + 16384 + 1024);             // aliases Cs+1KB

    const int t  = threadIdx.x;
    const int tx = t & 15;
    const int ty = t >> 4;
    const int v0 = blockIdx.x * 128;

    float acc[8][16];
    float z2p[8];
#pragma unroll
    for (int i = 0; i < 8; ++i) {
        z2p[i] = 0.f;
#pragma unroll
        for (int j = 0; j < 16; ++j) acc[i][j] = 0.f;
    }

    const int svl = t >> 1;
    const int skf = (t & 1) * 16;

    for (int k0 = 0; k0 < DDIM; k0 += 32) {
        __syncthreads();
        {
            const float4* src = (const float4*)&z[(long long)(v0 + svl) * DDIM + k0 + skf];
#pragma unroll
            for (int q = 0; q < 4; ++q) {
                float4 f = src[q];
                Zs[skf + q * 4 + 0][svl] = f.x;
                Zs[skf + q * 4 + 1][svl] = f.y;
                Zs[skf + q * 4 + 2][svl] = f.z;
                Zs[skf + q * 4 + 3][svl] = f.w;
            }
        }
        {
            const float4* src = (const float4*)&cb[(long long)t * DDIM + k0];
#pragma unroll
            for (int q = 0; q < 8; ++q) {
                float4 f = src[q];
                Cs[q * 4 + 0][t] = f.x;
                Cs[q * 4 + 1][t] = f.y;
                Cs[q * 4 + 2][t] = f.z;
                Cs[q * 4 + 3][t] = f.w;
            }
        }
        __syncthreads();

#pragma unroll 8
        for (int k = 0; k < 32; ++k) {
            float4 a0 = *(const float4*)&Zs[k][ty * 8];
            float4 a1 = *(const float4*)&Zs[k][ty * 8 + 4];
            float a[8] = {a0.x, a0.y, a0.z, a0.w, a1.x, a1.y, a1.z, a1.w};
            float b[16];
#pragma unroll
            for (int j = 0; j < 16; ++j) b[j] = Cs[k][tx + 16 * j];
#pragma unroll
            for (int i = 0; i < 8; ++i) z2p[i] += a[i] * a[i];
#pragma unroll
            for (int j = 0; j < 16; ++j)
#pragma unroll
                for (int i = 0; i < 8; ++i)
                    acc[i][j] += a[i] * b[j];
        }
    }

    __syncthreads();
    float c2v[16];
#pragma unroll
    for (int j = 0; j < 16; ++j) c2v[j] = c2[tx + 16 * j];
    lhist[t] = 0;
#pragma unroll
    for (int i = 0; i < 8; ++i) {
        float bd = 3.4e38f;
        int bj = 0;
#pragma unroll
        for (int j = 0; j < 16; ++j) {
            float d = (z2p[i] - 2.f * acc[i][j]) + c2v[j];
            if (d < bd) { bd = d; bj = j; }
        }
        red[(ty * 8 + i) * 16 + tx] =
            ((unsigned long long)__float_as_uint(bd) << 32) | (unsigned)(tx + 16 * bj);
    }
    __syncthreads();

    if (t < 128) {
        unsigned long long m = red[t * 16];
#pragma unroll
        for (int j = 1; j < 16; ++j) {
            unsigned long long c = red[t * 16 + j];
            if (c < m) m = c;
        }
        int bk = (int)(m & 0xffffffffu);
        bestk_sh[t] = bk;
        idx_out[v0 + t] = (float)bk;
        atomicAdd(&lhist[bk], 1);
    }
    __syncthreads();

    {
        const int zl = t >> 1, half = t & 1;
        const int bk = bestk_sh[zl];
        const float4* zp = (const float4*)&z[(long long)(v0 + zl) * DDIM + half * 64];
        const float4* cp = (const float4*)&cb[(long long)bk * DDIM + half * 64];
        uint4* zqp = (uint4*)&zq[(long long)(v0 + zl) * DDIM + half * 64];
        float lsum = 0.f;
#pragma unroll
        for (int q = 0; q < 8; ++q) {
            float4 z0 = zp[q * 2], z1 = zp[q * 2 + 1];
            float4 c0 = cp[q * 2], c1 = cp[q * 2 + 1];
            float dx, dy, dz, dw;
            dx = c0.x - z0.x; dy = c0.y - z0.y; dz = c0.z - z0.z; dw = c0.w - z0.w;
            lsum += dx * dx + dy * dy + dz * dz + dw * dw;
            dx = c1.x - z1.x; dy = c1.y - z1.y; dz = c1.z - z1.z; dw = c1.w - z1.w;
            lsum += dx * dx + dy * dy + dz * dz + dw * dw;
            uint4 pk;
            pk.x = (unsigned)f2b(c0.x) | ((unsigned)f2b(c0.y) << 16);
            pk.y = (unsigned)f2b(c0.z) | ((unsigned)f2b(c0.w) << 16);
            pk.z = (unsigned)f2b(c1.x) | ((unsigned)f2b(c1.y) << 16);
            pk.w = (unsigned)f2b(c1.z) | ((unsigned)f2b(c1.w) << 16);
            zqp[q] = pk;
        }
#pragma unroll
        for (int o = 32; o > 0; o >>= 1) lsum += __shfl_xor(lsum, o);
        if ((t & 63) == 0) atomicAdd(loss_sum, lsum);
    }
    __syncthreads();
    int h = lhist[t];
    if (h) atomicAdd(&hist[t], h);
}

// ---------------- finalize ----------------
__global__ __launch_bounds__(256)
void finalize_kernel(const int* __restrict__ hist, const float* __restrict__ loss,
                     float* __restrict__ out)
{
    __shared__ float red[256];
    const int t = threadIdx.x;
    float e = (float)hist[t] / (float)BG;
    red[t] = -e * logf(e + 1e-10f);
    __syncthreads();
    for (int s = 128; s > 0; s >>= 1) {
        if (t < s) red[t] += red[t + s];
        __syncthreads();
    }
    if (t == 0) {
        out[0]       = (1.f + BETA) * (*loss) / (float)((long long)BG * DDIM);
        out[PPL_OFF] = expf(red[0]);
    }
}

// ---------------- launch ----------------
extern "C" void kernel_launch(void* const* d_in, const int* in_sizes, int n_in,
                              void* d_out, int out_size, void* d_ws, size_t ws_size,
                              hipStream_t stream)
{
    const float* x        = (const float*)d_in[0];
    const float* enc_w1   = (const float*)d_in[1];
    const float* enc_b1   = (const float*)d_in[2];
    const float* enc_w2   = (const float*)d_in[3];
    const float* enc_b2   = (const float*)d_in[4];
    const float* ln_g     = (const float*)d_in[5];
    const float* ln_b     = (const float*)d_in[6];
    const float* enc_w3   = (const float*)d_in[7];
    const float* enc_b3   = (const float*)d_in[8];
    const float* enc_w4   = (const float*)d_in[9];
    const float* enc_b4   = (const float*)d_in[10];
    const float* codebook = (const float*)d_in[11];
    const float* dec_w1   = (const float*)d_in[12];
    const float* dec_b1   = (const float*)d_in[13];
    const float* dec_w2   = (const float*)d_in[14];
    const float* dec_b2   = (const float*)d_in[15];
    const float* dec_w3   = (const float*)d_in[16];
    const float* dec_b3   = (const float*)d_in[17];
    float* out = (float*)d_out;

    constexpr size_t RESERVE = 8ull << 20;
    char* ws = (char*)d_ws;
    ushort* wt1 = (ushort*)ws;                          // [1024][1024] bf16, 2MB
    ushort* wt2 = (ushort*)(ws + (2ull << 20));         // [1024][1024] bf16, 2MB
    ushort* wt3 = (ushort*)(ws + (4ull << 20));         // [128][1024] bf16 zero-padded
    float*  c2  = (float*)(ws + (4ull << 20) + 262144);
    int*   hist = (int*)  (ws + (4ull << 20) + 262144 + 1024);
    float* loss = (float*)(ws + (4ull << 20) + 262144 + 2048);

    static const int cands[9] = {32768, 16384, 8192, 4096, 2048, 1024, 512, 256, 128};
    int chunk = 128;
    for (int i = 0; i < 9; ++i) {
        size_t need = RESERVE + 2ull * (size_t)cands[i] * HDIM * sizeof(float);
        if (need <= ws_size) { chunk = cands[i]; break; }
    }
    float* bufA = (float*)(ws + RESERVE);
    float* bufB = (float*)(ws + RESERVE + (size_t)chunk * HDIM * sizeof(float));

    const dim3 blk(256);

    zero_kernel<<<1, 512, 0, stream>>>(hist, loss);
    c2_kernel<<<1, 256, 0, stream>>>(codebook, c2);
    transpose_to_bf16<<<dim3(32, 32), blk, 0, stream>>>(dec_w1, wt1, HDIM, HDIM, HDIM);
    transpose_to_bf16<<<dim3(32, 32), blk, 0, stream>>>(dec_w2, wt2, HDIM, HDIM, HDIM);
    transpose_to_bf16<<<dim3(4, 32),  blk, 0, stream>>>(dec_w3, wt3, HDIM, STATE_N, 128);

    for (int c0 = 0; c0 < BATCH; c0 += chunk) {
        const float* xc = x + (long long)c0 * STATE_N;
        float* decC     = out + DEC_OFF + (long long)c0 * STATE_N;
        float* idxC     = out + IDX_OFF + (long long)c0 * GGRP;

        // ---- encoder (fp32, K-step 32, bit-identical k-order) ----
        sgemm32<1><<<dim3(8, chunk / 128), blk, 0, stream>>>(xc,   enc_w1, enc_b1, bufA, chunk, HDIM, STATE_N);
        sgemm32<0><<<dim3(8, chunk / 128), blk, 0, stream>>>(bufA, enc_w2, enc_b2, bufB, chunk, HDIM, HDIM);
        ln_relu_kernel<<<chunk / 4, 256, 0, stream>>>(bufB, ln_g, ln_b, chunk);
        sgemm32<1><<<dim3(8, chunk / 128), blk, 0, stream>>>(bufB, enc_w3, enc_b3, bufA, chunk, HDIM, HDIM);
        sgemm32<0><<<dim3(1, chunk * GGRP / 128), blk, 0, stream>>>(bufA, enc_w4, enc_b4, bufB, chunk * GGRP, DDIM, DDIM);

        // ---- VQ (GEMM-structured fp32; writes bf16 z_q into bufA region) ----
        ushort* zqb = (ushort*)bufA;
        vq_gemm_kernel<<<chunk * GGRP / 128, blk, 0, stream>>>(bufB, codebook, c2, zqb, idxC, loss, hist);

        // ---- decoder (bf16 MFMA) ----
        ushort* g1b = (ushort*)bufB;
        ushort* g2b = (ushort*)(((char*)bufA) + (size_t)chunk * HDIM * sizeof(ushort));
        hgemm128<1, 1><<<dim3(8, chunk / 128), blk, 0, stream>>>(zqb, wt1, dec_b1, g1b, chunk, HDIM, HDIM);
        hgemm128<1, 1><<<dim3(8, chunk / 128), blk, 0, stream>>>(g1b, wt2, dec_b2, g2b, chunk, HDIM, HDIM);
        hgemm128<0, 0><<<dim3(1, chunk / 128), blk, 0, stream>>>(g2b, wt3, dec_b3, decC, chunk, STATE_N, HDIM);
    }

    finalize_kernel<<<1, 256, 0, stream>>>(hist, loss, out);
}